// Round 5
// baseline (414.439 us; speedup 1.0000x reference)
//
#include <hip/hip_runtime.h>
#include <hip/hip_bf16.h>

typedef __bf16 bf16x8 __attribute__((ext_vector_type(8)));
typedef __bf16 bf16x4 __attribute__((ext_vector_type(4)));
typedef float floatx4 __attribute__((ext_vector_type(4)));

#define LDW 128  // activation row stride (elems); XOR-swizzled, no pad
#define PXW 8    // pre_msg row stride: cols 0..2 recv-x, 3..5 self-x, 6..7 pad

// LDS act tile [96][128] bf16, swizzle: elem = row*128 + (col ^ ((row&7)<<3))
#define SWZ(row, col) ((row) * LDW + ((col) ^ (((row) & 7) << 3)))

// ws layout (bf16 element offsets). Big mats: Wt[n][k]. K32 pads: [128 n][32 k].
// N16 tails: [16 n][128 k].
#define O_E1W2  0
#define O_E2W1  16384
#define O_E2W2  49152
#define O_E3W1  65536
#define O_E3W2  81920
#define O_E4W1  98304
#define O_E4W2  131072
#define O_DM2T0 147456
#define O_DM2T1 163840
#define O_DO1   180224
#define O_DO2   196608
#define O_EWOUT 212992
#define O_DW3   215040
#define O_E1W1P 217088
#define O_M1T0P 221184
#define O_M1T1P 225280
#define O_DO1XP 229376
#define WS_ELEMS 233472

__global__ void prep_kernel(const float* e1w2, const float* e2w1, const float* e2w2,
    const float* e3w1, const float* e3w2, const float* e4w1, const float* e4w2,
    const float* dmsg2, const float* dout1, const float* dout2,
    const float* ew_out, const float* dout_w3, const float* e1w1,
    const float* dmsg_w1, __hip_bfloat16* ws) {
  int idx = blockIdx.x * 256 + threadIdx.x;
  if (idx >= WS_ELEMS) return;
  float v;
  if (idx < O_E2W1)      { int l = idx;           v = e1w2[(l & 127) * 128 + (l >> 7)]; }
  else if (idx < O_E2W2) { int l = idx - O_E2W1;  v = e2w1[(l & 255) * 128 + (l >> 8)]; }
  else if (idx < O_E3W1) { int l = idx - O_E2W2;  v = e2w2[(l & 127) * 128 + (l >> 7)]; }
  else if (idx < O_E3W2) { int l = idx - O_E3W1;  v = e3w1[(l & 127) * 128 + (l >> 7)]; }
  else if (idx < O_E4W1) { int l = idx - O_E3W2;  v = e3w2[(l & 127) * 128 + (l >> 7)]; }
  else if (idx < O_E4W2) { int l = idx - O_E4W1;  v = e4w1[(l & 255) * 128 + (l >> 8)]; }
  else if (idx < O_DM2T0){ int l = idx - O_E4W2;  v = e4w2[(l & 127) * 128 + (l >> 7)]; }
  else if (idx < O_DM2T1){ int l = idx - O_DM2T0; v = dmsg2[(l & 127) * 128 + (l >> 7)]; }
  else if (idx < O_DO1)  { int l = idx - O_DM2T1; v = dmsg2[16384 + (l & 127) * 128 + (l >> 7)]; }
  else if (idx < O_DO2)  { int l = idx - O_DO1;   v = dout1[384 + (l & 127) * 128 + (l >> 7)]; }
  else if (idx < O_EWOUT){ int l = idx - O_DO2;   v = dout2[(l & 127) * 128 + (l >> 7)]; }
  else if (idx < O_DW3)  { int l = idx - O_EWOUT; int n = l >> 7;
                           v = (n < 2) ? ew_out[(l & 127) * 2 + n] : 0.f; }
  else if (idx < O_E1W1P){ int l = idx - O_DW3;   int n = l >> 7;
                           v = (n < 3) ? dout_w3[(l & 127) * 3 + n] : 0.f; }
  else if (idx < O_M1T0P){ int l = idx - O_E1W1P; int n = l >> 5, c = l & 31;
                           v = (c >= 3 && c < 6) ? e1w1[(c - 3) * 128 + n] : 0.f; }
  else if (idx < O_M1T1P){ int l = idx - O_M1T0P; int n = l >> 5, c = l & 31;
                           v = (c < 6) ? dmsg_w1[c * 128 + n] : 0.f; }
  else if (idx < O_DO1XP){ int l = idx - O_M1T1P; int n = l >> 5, c = l & 31;
                           v = (c < 6) ? dmsg_w1[768 + c * 128 + n] : 0.f; }
  else                   { int l = idx - O_DO1XP; int n = l >> 5, c = l & 31;
                           v = (c >= 3 && c < 6) ? dout1[(c - 3) * 128 + n] : 0.f; }
  ws[idx] = __float2bfloat16(v);
}

struct W2 { bf16x8 b[2][4]; };   // [ct][ks] — 2 col-groups of a [n][128] weight
struct WK { bf16x8 k[2]; };      // [ct]    — K32-padded weight frags
struct B2 { floatx4 v[2]; };     // [ct]    — bias frags
union PK { bf16x4 v; __hip_bfloat16 h[4]; };

// Round-5: 2x4 wave re-tile. Wave (rw,cw) owns 48 rows (3 mt) x 32 cols (2 ct).
// Each LDS B-frag read feeds TWO MFMAs (was one) -> per-stage LDS reads halve
// (192KB -> 96KB per block-stage). Weight traffic doubles but rides L2, not
// the LDS pipe. MFMA count unchanged. LDS pipe was ~50-60% of wall (R4 model).
__global__ __launch_bounds__(512, 4) void nri_fused(
    const float* __restrict__ x,
    const float* __restrict__ e1b1, const float* __restrict__ e1b2,
    const float* __restrict__ e2b1, const float* __restrict__ e2b2,
    const float* __restrict__ e3b1, const float* __restrict__ e3b2,
    const float* __restrict__ e4b1, const float* __restrict__ e4b2,
    const float* __restrict__ eb_out,
    const float* __restrict__ dmsg_b1, const float* __restrict__ dmsg_b2,
    const float* __restrict__ dout_b1, const float* __restrict__ dout_b2,
    const float* __restrict__ dout_b3,
    const __bf16* __restrict__ wt, float* __restrict__ out)
{
  const int tid  = threadIdx.x;
  const int wave = tid >> 6;
  const int lane = tid & 63;
  const int nl   = lane & 15;
  const int quad = lane >> 4;
  const int rw   = wave >> 2;      // row half: rows rw*48 .. rw*48+47
  const int cw   = wave & 3;       // col quarter: cols cw*32 .. cw*32+31
  const int rb   = rw * 48;
  const int cb   = cw * 32;
  const int gx   = blockIdx.x * 288;

  __shared__ __align__(16) __hip_bfloat16 bufA[96 * LDW];   // 24576 B
  __shared__ __align__(16) __hip_bfloat16 bufB[96 * LDW];   // 24576 B
  __shared__ __align__(16) __hip_bfloat16 pxb[96 * PXW];    // 1536 B
  __shared__ __hip_bfloat16 rtw[192];                        // 384 B

  // ---- early global prefetch (no LDS dependency) ----
  B2 b_s1 = { *(const floatx4*)(e1b1 + cb + quad * 4),
              *(const floatx4*)(e1b1 + cb + 16 + quad * 4) };
  WK wk_s1;
#pragma unroll
  for (int ct = 0; ct < 2; ++ct)
    wk_s1.k[ct] = *(const bf16x8*)(wt + O_E1W1P + (cb + ct * 16 + nl) * 32 + quad * 8);

  // ---- stage 0: pre_msg staging ----
  for (int i = tid; i < 96 * PXW; i += 512) {
    int row = i >> 3, c = i & 7;
    int e = row % 6;
    float v = 0.f;
    if (c < 3)      { int rr = row + ((e == 5) ? -5 : 1); v = x[gx + rr * 3 + c]; }
    else if (c < 6) v = x[gx + row * 3 + (c - 3)];
    pxb[i] = __float2bfloat16(v);
  }
  __syncthreads();

  // ---- helpers ----
  auto ldb = [&](const float* p, int ofs) {
    B2 r;
    r.v[0] = *(const floatx4*)(p + ofs + cb + quad * 4);
    r.v[1] = *(const floatx4*)(p + ofs + cb + 16 + quad * 4);
    return r;
  };
  auto initv = [&](floatx4 (&a)[3][2], const B2& b) {
#pragma unroll
    for (int mt = 0; mt < 3; ++mt)
#pragma unroll
      for (int ct = 0; ct < 2; ++ct) a[mt][ct] = b.v[ct];
  };
  auto loadW128 = [&](int wofs) {
    W2 w;
#pragma unroll
    for (int ct = 0; ct < 2; ++ct) {
      const __bf16* p = wt + wofs + (cb + ct * 16 + nl) * 128 + quad * 8;
#pragma unroll
      for (int ks = 0; ks < 4; ++ks) w.b[ct][ks] = *(const bf16x8*)(p + ks * 32);
    }
    return w;
  };
  auto loadW256h = [&](int wofs, int kh) {
    W2 w;
#pragma unroll
    for (int ct = 0; ct < 2; ++ct) {
      const __bf16* p = wt + wofs + (cb + ct * 16 + nl) * 256 + kh * 128 + quad * 8;
#pragma unroll
      for (int ks = 0; ks < 4; ++ks) w.b[ct][ks] = *(const bf16x8*)(p + ks * 32);
    }
    return w;
  };
  auto loadWK = [&](int wofs) {
    WK w;
#pragma unroll
    for (int ct = 0; ct < 2; ++ct)
      w.k[ct] = *(const bf16x8*)(wt + wofs + (cb + ct * 16 + nl) * 32 + quad * 8);
    return w;
  };

  // K=128 GEMM: one B read feeds 2 MFMAs (ct groups). shift = ring-row read.
  auto gemmP = [&](floatx4 (&acc)[3][2], const W2& w, const __hip_bfloat16* in,
                   bool shift) {
    const __bf16* ab = (const __bf16*)(const void*)in;
    int rows[3];
#pragma unroll
    for (int mt = 0; mt < 3; ++mt) {
      int r = rb + mt * 16 + nl;
      rows[mt] = shift ? (r + ((r % 6 == 5) ? -5 : 1)) : r;
    }
#pragma unroll
    for (int ks = 0; ks < 4; ++ks) {
      int kk = ks * 32 + quad * 8;
#pragma unroll
      for (int mt = 0; mt < 3; ++mt) {
        bf16x8 b = *(const bf16x8*)(ab + SWZ(rows[mt], kk));
#pragma unroll
        for (int ct = 0; ct < 2; ++ct)
          acc[mt][ct] = __builtin_amdgcn_mfma_f32_16x16x32_bf16(w.b[ct][ks], b, acc[mt][ct], 0, 0, 0);
      }
    }
  };
  // shared-B dual GEMM (s5): one B read feeds 4 MFMAs
  auto gemmP2 = [&](floatx4 (&a1)[3][2], const W2& w1, floatx4 (&a2)[3][2],
                    const W2& w2v, const __hip_bfloat16* in) {
    const __bf16* ab = (const __bf16*)(const void*)in;
#pragma unroll
    for (int ks = 0; ks < 4; ++ks) {
      int kk = ks * 32 + quad * 8;
#pragma unroll
      for (int mt = 0; mt < 3; ++mt) {
        bf16x8 b = *(const bf16x8*)(ab + SWZ(rb + mt * 16 + nl, kk));
#pragma unroll
        for (int ct = 0; ct < 2; ++ct) {
          a1[mt][ct] = __builtin_amdgcn_mfma_f32_16x16x32_bf16(w1.b[ct][ks], b, a1[mt][ct], 0, 0, 0);
          a2[mt][ct] = __builtin_amdgcn_mfma_f32_16x16x32_bf16(w2v.b[ct][ks], b, a2[mt][ct], 0, 0, 0);
        }
      }
    }
  };
  // K=32 GEMM vs pxb; only quad 0 carries data.
  auto gemm32 = [&](floatx4 (&acc)[3][2], const WK& w) {
    const __bf16* pb = (const __bf16*)(const void*)pxb;
#pragma unroll
    for (int mt = 0; mt < 3; ++mt) {
      bf16x8 b = {0, 0, 0, 0, 0, 0, 0, 0};
      if (quad == 0) b = *(const bf16x8*)(pb + (rb + mt * 16 + nl) * PXW);
#pragma unroll
      for (int ct = 0; ct < 2; ++ct)
        acc[mt][ct] = __builtin_amdgcn_mfma_f32_16x16x32_bf16(w.k[ct], b, acc[mt][ct], 0, 0, 0);
    }
  };
  // epilogue: act 0=none 1=ELU 2=ReLU; shift = write to ring-shifted row (agg)
  auto store_act = [&](floatx4 (&acc)[3][2], int act, __hip_bfloat16* ob,
                       bool shift) {
#pragma unroll
    for (int mt = 0; mt < 3; ++mt) {
      int r = rb + mt * 16 + nl;
      int row = shift ? (r + ((r % 6 == 5) ? -5 : 1)) : r;
      int s = (row & 7) << 3;
#pragma unroll
      for (int ct = 0; ct < 2; ++ct) {
        PK p;
#pragma unroll
        for (int j = 0; j < 4; ++j) {
          float z = acc[mt][ct][j];
          if (act == 1) z = (z > 0.f) ? z : (__expf(z) - 1.f);
          else if (act == 2) z = fmaxf(z, 0.f);
          p.h[j] = __float2bfloat16(z);
        }
        *(bf16x4*)((__bf16*)(void*)ob + row * LDW + ((cb + ct * 16 + quad * 4) ^ s)) = p.v;
      }
    }
  };

  floatx4 acc[3][2], acc2[3][2];

  // s1: hh = ELU(x @ e1w1 + b) [K32]; prefetch e1w2 + e1b2
  initv(acc, b_s1); gemm32(acc, wk_s1);
  W2 w2 = loadW128(O_E1W2);
  B2 b_s2 = ldb(e1b2, 0);
  store_act(acc, 1, bufA, false);
  __syncthreads();
  // s2: h = ELU(. @ e1w2 + b); prefetch e2w1 recv-half + e2b1
  initv(acc, b_s2); gemmP(acc, w2, bufA, false);
  W2 w3a = loadW256h(O_E2W1, 0);
  B2 b_s3 = ldb(e2b1, 0);
  store_act(acc, 1, bufB, false);
  __syncthreads();
  // s3: ELU([h_recv|h] @ e2w1 + b): recv half with w3a (shifted rows), then
  // self half with w3b (issued first so its latency hides under gemm #1)
  initv(acc, b_s3);
  W2 w3b = loadW256h(O_E2W1, 1);
  gemmP(acc, w3a, bufB, true);
  gemmP(acc, w3b, bufB, false);
  W2 w4 = loadW128(O_E2W2);
  B2 b_s4 = ldb(e2b2, 0);
  store_act(acc, 1, bufA, false);
  __syncthreads();
  // s4: he = ELU(. @ e2w2 + b) -> bufB; prefetch e3w1 + e4w1[128:] + biases
  initv(acc, b_s4); gemmP(acc, w4, bufA, false);
  W2 w5 = loadW128(O_E3W1);
  W2 w5b = loadW256h(O_E4W1, 1);
  B2 b_s5 = ldb(e3b1, 0);
  B2 b2_s5 = ldb(e4b1, 0);
  store_act(acc, 1, bufB, false);
  __syncthreads();
  // s5: t1 = ELU(he @ e3w1 + b) -> bufA; acc2 = e4b1 + he @ e4w1[128:] (held)
  initv(acc, b_s5); initv(acc2, b2_s5);
  gemmP2(acc, w5, acc2, w5b, bufB);
  W2 w6 = loadW128(O_E3W2);
  B2 b_s6 = ldb(e3b2, 0);
  store_act(acc, 1, bufA, false);
  __syncthreads();
  // s6: h2 = ELU(t1 @ e3w2 + b) -> bufB (he dead); prefetch e4w1[:128]
  initv(acc, b_s6); gemmP(acc, w6, bufA, false);
  W2 w7 = loadW256h(O_E4W1, 0);
  store_act(acc, 1, bufB, false);
  __syncthreads();
  // s7: h3h = ELU(acc2 + h2 @ e4w1[:128]) -> bufA; prefetch e4w2 + e4b2
  gemmP(acc2, w7, bufB, false);
  W2 w8 = loadW128(O_E4W2);
  B2 b_s8 = ldb(e4b2, 0);
  store_act(acc2, 1, bufA, false);
  __syncthreads();
  // s8: h3 = ELU(. @ e4w2 + b) -> bufB; prefetch s9/s10 small weights+biases
  initv(acc, b_s8); gemmP(acc, w8, bufA, false);
  float ebv = (nl < 2) ? eb_out[nl] : 0.f;
  WK wk10a = loadWK(O_M1T0P);
  WK wk10b = loadWK(O_M1T1P);
  B2 b_m0 = ldb(dmsg_b1, 0);
  B2 b_m1 = ldb(dmsg_b1, 128);
  store_act(acc, 1, bufB, false);
  __syncthreads();

  // s9: logits via N=16-padded MFMA tail (waves 0..5, 16 rows each)
  if (wave < 6) {
    int tile = wave;
    floatx4 lg = {ebv, ebv, ebv, ebv};
    const __bf16* ab = (const __bf16*)(const void*)bufB;
    const __bf16* wp = wt + O_EWOUT + nl * 128 + quad * 8;
#pragma unroll
    for (int ks = 0; ks < 4; ++ks) {
      bf16x8 a = *(const bf16x8*)(ab + SWZ(tile * 16 + nl, ks * 32 + quad * 8));
      bf16x8 b = *(const bf16x8*)(wp + ks * 32);
      lg = __builtin_amdgcn_mfma_f32_16x16x32_bf16(a, b, lg, 0, 0, 0);
    }
    if (nl < 2) {
#pragma unroll
      for (int r = 0; r < 4; ++r)
        rtw[(tile * 16 + quad * 4 + r) * 2 + nl] = __float2bfloat16(lg[r]);
    }
  }
  __syncthreads();

  // s10: softmax + m1 both types [K32]: t0->bufA, t1->bufB; prefetch dm2
  if (tid < 96) {
    float l0 = __bfloat162float(rtw[tid * 2]);
    float l1 = __bfloat162float(rtw[tid * 2 + 1]);
    float mx = fmaxf(l0, l1);
    float ea = __expf(l0 - mx), eb = __expf(l1 - mx);
    float inv = 1.f / (ea + eb);
    rtw[tid * 2] = __float2bfloat16(ea * inv);
    rtw[tid * 2 + 1] = __float2bfloat16(eb * inv);
  }
  initv(acc, b_m0);  gemm32(acc, wk10a);  store_act(acc, 2, bufA, false);
  initv(acc2, b_m1); gemm32(acc2, wk10b); store_act(acc2, 2, bufB, false);
  W2 wm0 = loadW128(O_DM2T0);
  W2 wm1 = loadW128(O_DM2T1);
  B2 b_d0 = ldb(dmsg_b2, 0);
  B2 b_d1 = ldb(dmsg_b2, 128);
  __syncthreads();

  // s11: msg = rt0*relu(m1t0 @ w2t0 + b) + rt1*relu(m1t1 @ w2t1 + b)
  initv(acc, b_d0);  gemmP(acc, wm0, bufA, false);
  initv(acc2, b_d1); gemmP(acc2, wm1, bufB, false);
#pragma unroll
  for (int mt = 0; mt < 3; ++mt) {
    int row = rb + mt * 16 + nl;
    float r0 = __bfloat162float(rtw[row * 2]);
    float r1 = __bfloat162float(rtw[row * 2 + 1]);
#pragma unroll
    for (int ct = 0; ct < 2; ++ct)
#pragma unroll
      for (int j = 0; j < 4; ++j)
        acc[mt][ct][j] = r0 * fmaxf(acc[mt][ct][j], 0.f) + r1 * fmaxf(acc2[mt][ct][j], 0.f);
  }
  W2 wd1 = loadW128(O_DO1);
  WK wk13 = loadWK(O_DO1XP);
  B2 b_p1 = ldb(dout_b1, 0);
  __syncthreads();

  // s12: agg (edge e -> node (e+1)%6): store msg to ring-shifted rows of bufA
  store_act(acc, 0, bufA, true);
  __syncthreads();

  // s13: p1 = relu([x|agg] @ d_out_w1 + b) -> bufB; prefetch d_out_w2 + b2
  initv(acc, b_p1); gemmP(acc, wd1, bufA, false); gemm32(acc, wk13);
  W2 wd2 = loadW128(O_DO2);
  B2 b_p2 = ldb(dout_b2, 0);
  store_act(acc, 2, bufB, false);
  __syncthreads();
  // s14: p2 = relu(. @ d_out_w2 + b) -> bufA; prefetch b3
  initv(acc, b_p2); gemmP(acc, wd2, bufB, false);
  float b3v = (nl < 3) ? dout_b3[nl] : 0.f;
  store_act(acc, 2, bufA, false);
  __syncthreads();

  // s15: out = x + p2 @ d_out_w3 + b3 (waves 0..5, direct global store)
  if (wave < 6) {
    int tile = wave;
    floatx4 d = {b3v, b3v, b3v, b3v};
    const __bf16* ab = (const __bf16*)(const void*)bufA;
    const __bf16* wp = wt + O_DW3 + nl * 128 + quad * 8;
#pragma unroll
    for (int ks = 0; ks < 4; ++ks) {
      bf16x8 a = *(const bf16x8*)(ab + SWZ(tile * 16 + nl, ks * 32 + quad * 8));
      bf16x8 b = *(const bf16x8*)(wp + ks * 32);
      d = __builtin_amdgcn_mfma_f32_16x16x32_bf16(a, b, d, 0, 0, 0);
    }
    if (nl < 3) {
#pragma unroll
      for (int r = 0; r < 4; ++r) {
        int row = tile * 16 + quad * 4 + r;
        out[gx + row * 3 + nl] = x[gx + row * 3 + nl] + d[r];
      }
    }
  }
}

extern "C" void kernel_launch(void* const* d_in, const int* in_sizes, int n_in,
                              void* d_out, int out_size, void* d_ws, size_t ws_size,
                              hipStream_t stream) {
  const float* x       = (const float*)d_in[0];
  const float* e1w1    = (const float*)d_in[3];
  const float* e1b1    = (const float*)d_in[4];
  const float* e1w2    = (const float*)d_in[5];
  const float* e1b2    = (const float*)d_in[6];
  const float* e2w1    = (const float*)d_in[7];
  const float* e2b1    = (const float*)d_in[8];
  const float* e2w2    = (const float*)d_in[9];
  const float* e2b2    = (const float*)d_in[10];
  const float* e3w1    = (const float*)d_in[11];
  const float* e3b1    = (const float*)d_in[12];
  const float* e3w2    = (const float*)d_in[13];
  const float* e3b2    = (const float*)d_in[14];
  const float* e4w1    = (const float*)d_in[15];
  const float* e4b1    = (const float*)d_in[16];
  const float* e4w2    = (const float*)d_in[17];
  const float* e4b2    = (const float*)d_in[18];
  const float* ew_out  = (const float*)d_in[19];
  const float* eb_out  = (const float*)d_in[20];
  const float* dmsg_w1 = (const float*)d_in[21];
  const float* dmsg_b1 = (const float*)d_in[22];
  const float* dmsg_w2 = (const float*)d_in[23];
  const float* dmsg_b2 = (const float*)d_in[24];
  const float* dout_w1 = (const float*)d_in[25];
  const float* dout_b1 = (const float*)d_in[26];
  const float* dout_w2 = (const float*)d_in[27];
  const float* dout_b2 = (const float*)d_in[28];
  const float* dout_w3 = (const float*)d_in[29];
  const float* dout_b3 = (const float*)d_in[30];

  prep_kernel<<<(WS_ELEMS + 255) / 256, 256, 0, stream>>>(
      e1w2, e2w1, e2w2, e3w1, e3w2, e4w1, e4w2, dmsg_w2, dout_w1, dout_w2,
      ew_out, dout_w3, e1w1, dmsg_w1, (__hip_bfloat16*)d_ws);

  nri_fused<<<32768 / 16, 512, 0, stream>>>(
      x, e1b1, e1b2, e2b1, e2b2, e3b1, e3b2, e4b1, e4b2, eb_out,
      dmsg_b1, dmsg_b2, dout_b1, dout_b2, dout_b3,
      (const __bf16*)d_ws, (float*)d_out);
}

// Round 6
// 377.300 us; speedup vs baseline: 1.0984x; 1.0984x over previous
//
#include <hip/hip_runtime.h>
#include <hip/hip_bf16.h>

typedef __bf16 bf16x8 __attribute__((ext_vector_type(8)));
typedef __bf16 bf16x4 __attribute__((ext_vector_type(4)));
typedef float floatx4 __attribute__((ext_vector_type(4)));

#define LDW 128  // activation row stride (elems); XOR-swizzled, no pad
#define PXW 8    // pre_msg row stride: cols 0..2 recv-x, 3..5 self-x, 6..7 pad

// LDS act tile [96][128] bf16, swizzle: elem = row*128 + (col ^ ((row&7)<<3))
#define SWZ(row, col) ((row) * LDW + ((col) ^ (((row) & 7) << 3)))

#define SCHED __builtin_amdgcn_sched_barrier(0)

// ws layout (bf16 element offsets). Big mats: Wt[n][k]. K32 pads: [128 n][32 k].
// N16 tails: [16 n][128 k].
#define O_E1W2  0
#define O_E2W1  16384
#define O_E2W2  49152
#define O_E3W1  65536
#define O_E3W2  81920
#define O_E4W1  98304
#define O_E4W2  131072
#define O_DM2T0 147456
#define O_DM2T1 163840
#define O_DO1   180224
#define O_DO2   196608
#define O_EWOUT 212992
#define O_DW3   215040
#define O_E1W1P 217088
#define O_M1T0P 221184
#define O_M1T1P 225280
#define O_DO1XP 229376
#define WS_ELEMS 233472

__global__ void prep_kernel(const float* e1w2, const float* e2w1, const float* e2w2,
    const float* e3w1, const float* e3w2, const float* e4w1, const float* e4w2,
    const float* dmsg2, const float* dout1, const float* dout2,
    const float* ew_out, const float* dout_w3, const float* e1w1,
    const float* dmsg_w1, __hip_bfloat16* ws) {
  int idx = blockIdx.x * 256 + threadIdx.x;
  if (idx >= WS_ELEMS) return;
  float v;
  if (idx < O_E2W1)      { int l = idx;           v = e1w2[(l & 127) * 128 + (l >> 7)]; }
  else if (idx < O_E2W2) { int l = idx - O_E2W1;  v = e2w1[(l & 255) * 128 + (l >> 8)]; }
  else if (idx < O_E3W1) { int l = idx - O_E2W2;  v = e2w2[(l & 127) * 128 + (l >> 7)]; }
  else if (idx < O_E3W2) { int l = idx - O_E3W1;  v = e3w1[(l & 127) * 128 + (l >> 7)]; }
  else if (idx < O_E4W1) { int l = idx - O_E3W2;  v = e3w2[(l & 127) * 128 + (l >> 7)]; }
  else if (idx < O_E4W2) { int l = idx - O_E4W1;  v = e4w1[(l & 255) * 128 + (l >> 8)]; }
  else if (idx < O_DM2T0){ int l = idx - O_E4W2;  v = e4w2[(l & 127) * 128 + (l >> 7)]; }
  else if (idx < O_DM2T1){ int l = idx - O_DM2T0; v = dmsg2[(l & 127) * 128 + (l >> 7)]; }
  else if (idx < O_DO1)  { int l = idx - O_DM2T1; v = dmsg2[16384 + (l & 127) * 128 + (l >> 7)]; }
  else if (idx < O_DO2)  { int l = idx - O_DO1;   v = dout1[384 + (l & 127) * 128 + (l >> 7)]; }
  else if (idx < O_EWOUT){ int l = idx - O_DO2;   v = dout2[(l & 127) * 128 + (l >> 7)]; }
  else if (idx < O_DW3)  { int l = idx - O_EWOUT; int n = l >> 7;
                           v = (n < 2) ? ew_out[(l & 127) * 2 + n] : 0.f; }
  else if (idx < O_E1W1P){ int l = idx - O_DW3;   int n = l >> 7;
                           v = (n < 3) ? dout_w3[(l & 127) * 3 + n] : 0.f; }
  else if (idx < O_M1T0P){ int l = idx - O_E1W1P; int n = l >> 5, c = l & 31;
                           v = (c >= 3 && c < 6) ? e1w1[(c - 3) * 128 + n] : 0.f; }
  else if (idx < O_M1T1P){ int l = idx - O_M1T0P; int n = l >> 5, c = l & 31;
                           v = (c < 6) ? dmsg_w1[c * 128 + n] : 0.f; }
  else if (idx < O_DO1XP){ int l = idx - O_M1T1P; int n = l >> 5, c = l & 31;
                           v = (c < 6) ? dmsg_w1[768 + c * 128 + n] : 0.f; }
  else                   { int l = idx - O_DO1XP; int n = l >> 5, c = l & 31;
                           v = (c >= 3 && c < 6) ? dout1[(c - 3) * 128 + n] : 0.f; }
  ws[idx] = __float2bfloat16(v);
}

struct W2 { bf16x8 b[2][4]; };   // [ct][ks] — 2 col-groups of a [n][128] weight
struct WK { bf16x8 k[2]; };      // [ct]    — K32-padded weight frags
struct B2 { floatx4 v[2]; };     // [ct]    — bias frags
union PK { bf16x4 v; __hip_bfloat16 h[4]; };

// Round-6: R5's 2x4 wave tile (48 rows x 32 cols -> LDS reads halved) with a
// spill-free weight liveness schedule: next-stage weight loads are placed
// AFTER the current gemm (weight regs dead) behind sched_barrier(0), and the
// dual-weight stages (s5, s11) are sequenced so at most one 32-reg weight set
// coexists with the two accumulator sets. R5 spilled at ~144 live regs.
__global__ __launch_bounds__(512, 4) void nri_fused(
    const float* __restrict__ x,
    const float* __restrict__ e1b1, const float* __restrict__ e1b2,
    const float* __restrict__ e2b1, const float* __restrict__ e2b2,
    const float* __restrict__ e3b1, const float* __restrict__ e3b2,
    const float* __restrict__ e4b1, const float* __restrict__ e4b2,
    const float* __restrict__ eb_out,
    const float* __restrict__ dmsg_b1, const float* __restrict__ dmsg_b2,
    const float* __restrict__ dout_b1, const float* __restrict__ dout_b2,
    const float* __restrict__ dout_b3,
    const __bf16* __restrict__ wt, float* __restrict__ out)
{
  const int tid  = threadIdx.x;
  const int wave = tid >> 6;
  const int lane = tid & 63;
  const int nl   = lane & 15;
  const int quad = lane >> 4;
  const int rw   = wave >> 2;      // row half: rows rw*48 .. rw*48+47
  const int cw   = wave & 3;       // col quarter: cols cw*32 .. cw*32+31
  const int rb   = rw * 48;
  const int cb   = cw * 32;
  const int gx   = blockIdx.x * 288;

  __shared__ __align__(16) __hip_bfloat16 bufA[96 * LDW];   // 24576 B
  __shared__ __align__(16) __hip_bfloat16 bufB[96 * LDW];   // 24576 B
  __shared__ __align__(16) __hip_bfloat16 pxb[96 * PXW];    // 1536 B
  __shared__ __hip_bfloat16 rtw[192];                        // 384 B

  // ---- early global prefetch (no LDS dependency) ----
  B2 b_s1 = { *(const floatx4*)(e1b1 + cb + quad * 4),
              *(const floatx4*)(e1b1 + cb + 16 + quad * 4) };
  WK wk_s1;
#pragma unroll
  for (int ct = 0; ct < 2; ++ct)
    wk_s1.k[ct] = *(const bf16x8*)(wt + O_E1W1P + (cb + ct * 16 + nl) * 32 + quad * 8);

  // ---- stage 0: pre_msg staging ----
  for (int i = tid; i < 96 * PXW; i += 512) {
    int row = i >> 3, c = i & 7;
    int e = row % 6;
    float v = 0.f;
    if (c < 3)      { int rr = row + ((e == 5) ? -5 : 1); v = x[gx + rr * 3 + c]; }
    else if (c < 6) v = x[gx + row * 3 + (c - 3)];
    pxb[i] = __float2bfloat16(v);
  }
  __syncthreads();

  // ---- helpers ----
  auto ldb = [&](const float* p, int ofs) {
    B2 r;
    r.v[0] = *(const floatx4*)(p + ofs + cb + quad * 4);
    r.v[1] = *(const floatx4*)(p + ofs + cb + 16 + quad * 4);
    return r;
  };
  auto initv = [&](floatx4 (&a)[3][2], const B2& b) {
#pragma unroll
    for (int mt = 0; mt < 3; ++mt)
#pragma unroll
      for (int ct = 0; ct < 2; ++ct) a[mt][ct] = b.v[ct];
  };
  auto loadW128 = [&](int wofs) {
    W2 w;
#pragma unroll
    for (int ct = 0; ct < 2; ++ct) {
      const __bf16* p = wt + wofs + (cb + ct * 16 + nl) * 128 + quad * 8;
#pragma unroll
      for (int ks = 0; ks < 4; ++ks) w.b[ct][ks] = *(const bf16x8*)(p + ks * 32);
    }
    return w;
  };
  auto loadW256h = [&](int wofs, int kh) {
    W2 w;
#pragma unroll
    for (int ct = 0; ct < 2; ++ct) {
      const __bf16* p = wt + wofs + (cb + ct * 16 + nl) * 256 + kh * 128 + quad * 8;
#pragma unroll
      for (int ks = 0; ks < 4; ++ks) w.b[ct][ks] = *(const bf16x8*)(p + ks * 32);
    }
    return w;
  };
  auto loadWK = [&](int wofs) {
    WK w;
#pragma unroll
    for (int ct = 0; ct < 2; ++ct)
      w.k[ct] = *(const bf16x8*)(wt + wofs + (cb + ct * 16 + nl) * 32 + quad * 8);
    return w;
  };

  // K=128 GEMM: one B read feeds 2 MFMAs (ct groups). shift = ring-row read.
  auto gemmP = [&](floatx4 (&acc)[3][2], const W2& w, const __hip_bfloat16* in,
                   bool shift) {
    const __bf16* ab = (const __bf16*)(const void*)in;
    int rows[3];
#pragma unroll
    for (int mt = 0; mt < 3; ++mt) {
      int r = rb + mt * 16 + nl;
      rows[mt] = shift ? (r + ((r % 6 == 5) ? -5 : 1)) : r;
    }
#pragma unroll
    for (int ks = 0; ks < 4; ++ks) {
      int kk = ks * 32 + quad * 8;
#pragma unroll
      for (int mt = 0; mt < 3; ++mt) {
        bf16x8 b = *(const bf16x8*)(ab + SWZ(rows[mt], kk));
#pragma unroll
        for (int ct = 0; ct < 2; ++ct)
          acc[mt][ct] = __builtin_amdgcn_mfma_f32_16x16x32_bf16(w.b[ct][ks], b, acc[mt][ct], 0, 0, 0);
      }
    }
  };
  // K=32 GEMM vs pxb; only quad 0 carries data.
  auto gemm32 = [&](floatx4 (&acc)[3][2], const WK& w) {
    const __bf16* pb = (const __bf16*)(const void*)pxb;
#pragma unroll
    for (int mt = 0; mt < 3; ++mt) {
      bf16x8 b = {0, 0, 0, 0, 0, 0, 0, 0};
      if (quad == 0) b = *(const bf16x8*)(pb + (rb + mt * 16 + nl) * PXW);
#pragma unroll
      for (int ct = 0; ct < 2; ++ct)
        acc[mt][ct] = __builtin_amdgcn_mfma_f32_16x16x32_bf16(w.k[ct], b, acc[mt][ct], 0, 0, 0);
    }
  };
  // epilogue: act 0=none 1=ELU 2=ReLU; shift = write to ring-shifted row (agg)
  auto store_act = [&](floatx4 (&acc)[3][2], int act, __hip_bfloat16* ob,
                       bool shift) {
#pragma unroll
    for (int mt = 0; mt < 3; ++mt) {
      int r = rb + mt * 16 + nl;
      int row = shift ? (r + ((r % 6 == 5) ? -5 : 1)) : r;
      int s = (row & 7) << 3;
#pragma unroll
      for (int ct = 0; ct < 2; ++ct) {
        PK p;
#pragma unroll
        for (int j = 0; j < 4; ++j) {
          float z = acc[mt][ct][j];
          if (act == 1) z = (z > 0.f) ? z : (__expf(z) - 1.f);
          else if (act == 2) z = fmaxf(z, 0.f);
          p.h[j] = __float2bfloat16(z);
        }
        *(bf16x4*)((__bf16*)(void*)ob + row * LDW + ((cb + ct * 16 + quad * 4) ^ s)) = p.v;
      }
    }
  };

  floatx4 acc[3][2], acc2[3][2];

  // s1: hh = ELU(x @ e1w1 + b) [K32]; then load e1w2 (wk_s1 dead after gemm)
  initv(acc, b_s1); gemm32(acc, wk_s1);
  SCHED;
  W2 w2 = loadW128(O_E1W2);
  B2 b_s2 = ldb(e1b2, 0);
  store_act(acc, 1, bufA, false);
  __syncthreads();

  // s2: h = ELU(. @ e1w2 + b); then load e2w1 recv-half
  initv(acc, b_s2); gemmP(acc, w2, bufA, false);
  SCHED;
  W2 w3a = loadW256h(O_E2W1, 0);
  B2 b_s3 = ldb(e2b1, 0);
  store_act(acc, 1, bufB, false);
  __syncthreads();

  // s3: ELU([h_recv|h] @ e2w1 + b). Single acc -> 2 weight sets affordable:
  // load self-half up front so it's in flight during the recv-half gemm.
  initv(acc, b_s3);
  W2 w3b = loadW256h(O_E2W1, 1);
  gemmP(acc, w3a, bufB, true);
  gemmP(acc, w3b, bufB, false);
  SCHED;
  W2 w4 = loadW128(O_E2W2);
  B2 b_s4 = ldb(e2b2, 0);
  store_act(acc, 1, bufA, false);
  __syncthreads();

  // s4: he = ELU(. @ e2w2 + b) -> bufB; then load e3w1 only (NOT e4w1 half)
  initv(acc, b_s4); gemmP(acc, w4, bufA, false);
  SCHED;
  W2 w5 = loadW128(O_E3W1);
  B2 b_s5 = ldb(e3b1, 0);
  B2 b2_s5 = ldb(e4b1, 0);
  store_act(acc, 1, bufB, false);
  __syncthreads();

  // s5: t1 = ELU(he @ e3w1 + b) -> bufA; THEN acc2 = e4b1 + he @ e4w1[128:]
  // sequenced: w5 dies before w5b loads (R5 held both + acc + acc2 -> spill)
  initv(acc, b_s5); gemmP(acc, w5, bufB, false);
  SCHED;
  W2 w5b = loadW256h(O_E4W1, 1);
  store_act(acc, 1, bufA, false);
  initv(acc2, b2_s5); gemmP(acc2, w5b, bufB, false);
  SCHED;
  W2 w6 = loadW128(O_E3W2);
  B2 b_s6 = ldb(e3b2, 0);
  __syncthreads();

  // s6: h2 = ELU(t1 @ e3w2 + b) -> bufB (he dead); acc2 stays live (+24 regs)
  initv(acc, b_s6); gemmP(acc, w6, bufA, false);
  SCHED;
  W2 w7 = loadW256h(O_E4W1, 0);
  store_act(acc, 1, bufB, false);
  __syncthreads();

  // s7: h3h = ELU(acc2 + h2 @ e4w1[:128]) -> bufA
  gemmP(acc2, w7, bufB, false);
  SCHED;
  W2 w8 = loadW128(O_E4W2);
  B2 b_s8 = ldb(e4b2, 0);
  store_act(acc2, 1, bufA, false);
  __syncthreads();

  // s8: h3 = ELU(. @ e4w2 + b) -> bufB; then small s9/s10 weights+biases
  initv(acc, b_s8); gemmP(acc, w8, bufA, false);
  SCHED;
  float ebv = (nl < 2) ? eb_out[nl] : 0.f;
  WK wk10a = loadWK(O_M1T0P);
  WK wk10b = loadWK(O_M1T1P);
  B2 b_m0 = ldb(dmsg_b1, 0);
  B2 b_m1 = ldb(dmsg_b1, 128);
  store_act(acc, 1, bufB, false);
  __syncthreads();

  // s9: logits via N=16-padded MFMA tail (waves 0..5, 16 rows each)
  if (wave < 6) {
    int tile = wave;
    floatx4 lg = {ebv, ebv, ebv, ebv};
    const __bf16* ab = (const __bf16*)(const void*)bufB;
    const __bf16* wp = wt + O_EWOUT + nl * 128 + quad * 8;
#pragma unroll
    for (int ks = 0; ks < 4; ++ks) {
      bf16x8 a = *(const bf16x8*)(ab + SWZ(tile * 16 + nl, ks * 32 + quad * 8));
      bf16x8 b = *(const bf16x8*)(wp + ks * 32);
      lg = __builtin_amdgcn_mfma_f32_16x16x32_bf16(a, b, lg, 0, 0, 0);
    }
    if (nl < 2) {
#pragma unroll
      for (int r = 0; r < 4; ++r)
        rtw[(tile * 16 + quad * 4 + r) * 2 + nl] = __float2bfloat16(lg[r]);
    }
  }
  __syncthreads();

  // s10: softmax + m1 both types [K32]: t0->bufA, t1->bufB; then load dm2t0
  if (tid < 96) {
    float l0 = __bfloat162float(rtw[tid * 2]);
    float l1 = __bfloat162float(rtw[tid * 2 + 1]);
    float mx = fmaxf(l0, l1);
    float ea = __expf(l0 - mx), eb = __expf(l1 - mx);
    float inv = 1.f / (ea + eb);
    rtw[tid * 2] = __float2bfloat16(ea * inv);
    rtw[tid * 2 + 1] = __float2bfloat16(eb * inv);
  }
  initv(acc, b_m0);  gemm32(acc, wk10a);  store_act(acc, 2, bufA, false);
  initv(acc2, b_m1); gemm32(acc2, wk10b); store_act(acc2, 2, bufB, false);
  SCHED;
  W2 wm0 = loadW128(O_DM2T0);
  B2 b_d0 = ldb(dmsg_b2, 0);
  B2 b_d1 = ldb(dmsg_b2, 128);
  __syncthreads();

  // s11: msg = rt0*relu(m1t0 @ w2t0 + b) + rt1*relu(m1t1 @ w2t1 + b)
  // sequenced: wm0 dies before wm1 loads (R5 held both + acc + acc2)
  initv(acc, b_d0);  gemmP(acc, wm0, bufA, false);
  SCHED;
  W2 wm1 = loadW128(O_DM2T1);
  initv(acc2, b_d1); gemmP(acc2, wm1, bufB, false);
  SCHED;
  W2 wd1 = loadW128(O_DO1);
  WK wk13 = loadWK(O_DO1XP);
  B2 b_p1 = ldb(dout_b1, 0);
#pragma unroll
  for (int mt = 0; mt < 3; ++mt) {
    int row = rb + mt * 16 + nl;
    float r0 = __bfloat162float(rtw[row * 2]);
    float r1 = __bfloat162float(rtw[row * 2 + 1]);
#pragma unroll
    for (int ct = 0; ct < 2; ++ct)
#pragma unroll
      for (int j = 0; j < 4; ++j)
        acc[mt][ct][j] = r0 * fmaxf(acc[mt][ct][j], 0.f) + r1 * fmaxf(acc2[mt][ct][j], 0.f);
  }
  __syncthreads();

  // s12: agg (edge e -> node (e+1)%6): store msg to ring-shifted rows of bufA
  store_act(acc, 0, bufA, true);
  __syncthreads();

  // s13: p1 = relu([x|agg] @ d_out_w1 + b) -> bufB; then load d_out_w2
  initv(acc, b_p1); gemmP(acc, wd1, bufA, false); gemm32(acc, wk13);
  SCHED;
  W2 wd2 = loadW128(O_DO2);
  B2 b_p2 = ldb(dout_b2, 0);
  store_act(acc, 2, bufB, false);
  __syncthreads();

  // s14: p2 = relu(. @ d_out_w2 + b) -> bufA
  initv(acc, b_p2); gemmP(acc, wd2, bufB, false);
  float b3v = (nl < 3) ? dout_b3[nl] : 0.f;
  store_act(acc, 2, bufA, false);
  __syncthreads();

  // s15: out = x + p2 @ d_out_w3 + b3 (waves 0..5, direct global store)
  if (wave < 6) {
    int tile = wave;
    floatx4 d = {b3v, b3v, b3v, b3v};
    const __bf16* ab = (const __bf16*)(const void*)bufA;
    const __bf16* wp = wt + O_DW3 + nl * 128 + quad * 8;
#pragma unroll
    for (int ks = 0; ks < 4; ++ks) {
      bf16x8 a = *(const bf16x8*)(ab + SWZ(tile * 16 + nl, ks * 32 + quad * 8));
      bf16x8 b = *(const bf16x8*)(wp + ks * 32);
      d = __builtin_amdgcn_mfma_f32_16x16x32_bf16(a, b, d, 0, 0, 0);
    }
    if (nl < 3) {
#pragma unroll
      for (int r = 0; r < 4; ++r) {
        int row = tile * 16 + quad * 4 + r;
        out[gx + row * 3 + nl] = x[gx + row * 3 + nl] + d[r];
      }
    }
  }
}

extern "C" void kernel_launch(void* const* d_in, const int* in_sizes, int n_in,
                              void* d_out, int out_size, void* d_ws, size_t ws_size,
                              hipStream_t stream) {
  const float* x       = (const float*)d_in[0];
  const float* e1w1    = (const float*)d_in[3];
  const float* e1b1    = (const float*)d_in[4];
  const float* e1w2    = (const float*)d_in[5];
  const float* e1b2    = (const float*)d_in[6];
  const float* e2w1    = (const float*)d_in[7];
  const float* e2b1    = (const float*)d_in[8];
  const float* e2w2    = (const float*)d_in[9];
  const float* e2b2    = (const float*)d_in[10];
  const float* e3w1    = (const float*)d_in[11];
  const float* e3b1    = (const float*)d_in[12];
  const float* e3w2    = (const float*)d_in[13];
  const float* e3b2    = (const float*)d_in[14];
  const float* e4w1    = (const float*)d_in[15];
  const float* e4b1    = (const float*)d_in[16];
  const float* e4w2    = (const float*)d_in[17];
  const float* e4b2    = (const float*)d_in[18];
  const float* ew_out  = (const float*)d_in[19];
  const float* eb_out  = (const float*)d_in[20];
  const float* dmsg_w1 = (const float*)d_in[21];
  const float* dmsg_b1 = (const float*)d_in[22];
  const float* dmsg_w2 = (const float*)d_in[23];
  const float* dmsg_b2 = (const float*)d_in[24];
  const float* dout_w1 = (const float*)d_in[25];
  const float* dout_b1 = (const float*)d_in[26];
  const float* dout_w2 = (const float*)d_in[27];
  const float* dout_b2 = (const float*)d_in[28];
  const float* dout_w3 = (const float*)d_in[29];
  const float* dout_b3 = (const float*)d_in[30];

  prep_kernel<<<(WS_ELEMS + 255) / 256, 256, 0, stream>>>(
      e1w2, e2w1, e2w2, e3w1, e3w2, e4w1, e4w2, dmsg_w2, dout_w1, dout_w2,
      ew_out, dout_w3, e1w1, dmsg_w1, (__hip_bfloat16*)d_ws);

  nri_fused<<<32768 / 16, 512, 0, stream>>>(
      x, e1b1, e1b2, e2b1, e2b2, e3b1, e3b2, e4b1, e4b2, eb_out,
      dmsg_b1, dmsg_b2, dout_b1, dout_b2, dout_b3,
      (const __bf16*)d_ws, (float*)d_out);
}

// Round 7
// 374.158 us; speedup vs baseline: 1.1077x; 1.0084x over previous
//
#include <hip/hip_runtime.h>
#include <hip/hip_bf16.h>

typedef __bf16 bf16x8 __attribute__((ext_vector_type(8)));
typedef __bf16 bf16x4 __attribute__((ext_vector_type(4)));
typedef float floatx4 __attribute__((ext_vector_type(4)));

#define LDW 128  // activation row stride (elems); XOR-swizzled, no pad
#define PXW 8    // pre_msg row stride: cols 0..2 recv-x, 3..5 self-x, 6..7 pad

// LDS act tile [96][128] bf16, swizzle: elem = row*128 + (col ^ ((row&7)<<3))
#define SWZ(row, col) ((row) * LDW + ((col) ^ (((row) & 7) << 3)))

#define SCHED __builtin_amdgcn_sched_barrier(0)

// ws layout (bf16 element offsets). Big mats: Wt[n][k]. K32 pads: [128 n][32 k].
// N16 tails: [16 n][128 k].
#define O_E1W2  0
#define O_E2W1  16384
#define O_E2W2  49152
#define O_E3W1  65536
#define O_E3W2  81920
#define O_E4W1  98304
#define O_E4W2  131072
#define O_DM2T0 147456
#define O_DM2T1 163840
#define O_DO1   180224
#define O_DO2   196608
#define O_EWOUT 212992
#define O_DW3   215040
#define O_E1W1P 217088
#define O_M1T0P 221184
#define O_M1T1P 225280
#define O_DO1XP 229376
#define WS_ELEMS 233472

__global__ void prep_kernel(const float* e1w2, const float* e2w1, const float* e2w2,
    const float* e3w1, const float* e3w2, const float* e4w1, const float* e4w2,
    const float* dmsg2, const float* dout1, const float* dout2,
    const float* ew_out, const float* dout_w3, const float* e1w1,
    const float* dmsg_w1, __hip_bfloat16* ws) {
  int idx = blockIdx.x * 256 + threadIdx.x;
  if (idx >= WS_ELEMS) return;
  float v;
  if (idx < O_E2W1)      { int l = idx;           v = e1w2[(l & 127) * 128 + (l >> 7)]; }
  else if (idx < O_E2W2) { int l = idx - O_E2W1;  v = e2w1[(l & 255) * 128 + (l >> 8)]; }
  else if (idx < O_E3W1) { int l = idx - O_E2W2;  v = e2w2[(l & 127) * 128 + (l >> 7)]; }
  else if (idx < O_E3W2) { int l = idx - O_E3W1;  v = e3w1[(l & 127) * 128 + (l >> 7)]; }
  else if (idx < O_E4W1) { int l = idx - O_E3W2;  v = e3w2[(l & 127) * 128 + (l >> 7)]; }
  else if (idx < O_E4W2) { int l = idx - O_E4W1;  v = e4w1[(l & 255) * 128 + (l >> 8)]; }
  else if (idx < O_DM2T0){ int l = idx - O_E4W2;  v = e4w2[(l & 127) * 128 + (l >> 7)]; }
  else if (idx < O_DM2T1){ int l = idx - O_DM2T0; v = dmsg2[(l & 127) * 128 + (l >> 7)]; }
  else if (idx < O_DO1)  { int l = idx - O_DM2T1; v = dmsg2[16384 + (l & 127) * 128 + (l >> 7)]; }
  else if (idx < O_DO2)  { int l = idx - O_DO1;   v = dout1[384 + (l & 127) * 128 + (l >> 7)]; }
  else if (idx < O_EWOUT){ int l = idx - O_DO2;   v = dout2[(l & 127) * 128 + (l >> 7)]; }
  else if (idx < O_DW3)  { int l = idx - O_EWOUT; int n = l >> 7;
                           v = (n < 2) ? ew_out[(l & 127) * 2 + n] : 0.f; }
  else if (idx < O_E1W1P){ int l = idx - O_DW3;   int n = l >> 7;
                           v = (n < 3) ? dout_w3[(l & 127) * 3 + n] : 0.f; }
  else if (idx < O_M1T0P){ int l = idx - O_E1W1P; int n = l >> 5, c = l & 31;
                           v = (c >= 3 && c < 6) ? e1w1[(c - 3) * 128 + n] : 0.f; }
  else if (idx < O_M1T1P){ int l = idx - O_M1T0P; int n = l >> 5, c = l & 31;
                           v = (c < 6) ? dmsg_w1[c * 128 + n] : 0.f; }
  else if (idx < O_DO1XP){ int l = idx - O_M1T1P; int n = l >> 5, c = l & 31;
                           v = (c < 6) ? dmsg_w1[768 + c * 128 + n] : 0.f; }
  else                   { int l = idx - O_DO1XP; int n = l >> 5, c = l & 31;
                           v = (c >= 3 && c < 6) ? dout1[(c - 3) * 128 + n] : 0.f; }
  ws[idx] = __float2bfloat16(v);
}

struct W2 { bf16x8 b[2][4]; };   // [ct][ks] — 2 col-groups of a [n][128] weight
struct WK { bf16x8 k[2]; };      // [ct]    — K32-padded weight frags
struct B2 { floatx4 v[2]; };     // [ct]    — bias frags
union PK { bf16x4 v; __hip_bfloat16 h[4]; };

// Round-7: ct=2 retile (halved LDS reads), spill-proofed:
//  (a) sched_barrier(0) per ks inside gemms -> B-frag batch <= 12 regs
//      (R5/R6 spilled because the scheduler batched all 12 reads = 48 regs)
//  (b) third LDS buffer keeps `he` in LDS across s5-s7 -> no acc2 held
//      across stages; s7 = two sequential single-acc gemms (bufB + bufC)
//  (c) dual-acc only in s10/s11, weight sets strictly sequenced.
// Worst-point liveness <= ~105 VGPR < the 128 cap at 16 waves/CU.
__global__ __launch_bounds__(512, 4) void nri_fused(
    const float* __restrict__ x,
    const float* __restrict__ e1b1, const float* __restrict__ e1b2,
    const float* __restrict__ e2b1, const float* __restrict__ e2b2,
    const float* __restrict__ e3b1, const float* __restrict__ e3b2,
    const float* __restrict__ e4b1, const float* __restrict__ e4b2,
    const float* __restrict__ eb_out,
    const float* __restrict__ dmsg_b1, const float* __restrict__ dmsg_b2,
    const float* __restrict__ dout_b1, const float* __restrict__ dout_b2,
    const float* __restrict__ dout_b3,
    const __bf16* __restrict__ wt, float* __restrict__ out)
{
  const int tid  = threadIdx.x;
  const int wave = tid >> 6;
  const int lane = tid & 63;
  const int nl   = lane & 15;
  const int quad = lane >> 4;
  const int rw   = wave >> 2;      // row half: rows rw*48 .. rw*48+47
  const int cw   = wave & 3;       // col quarter: cols cw*32 .. cw*32+31
  const int rb   = rw * 48;
  const int cb   = cw * 32;
  const int gx   = blockIdx.x * 288;

  __shared__ __align__(16) __hip_bfloat16 bufA[96 * LDW];   // 24576 B
  __shared__ __align__(16) __hip_bfloat16 bufB[96 * LDW];   // 24576 B
  __shared__ __align__(16) __hip_bfloat16 bufC[96 * LDW];   // 24576 B
  __shared__ __align__(16) __hip_bfloat16 pxb[96 * PXW];    // 1536 B
  __shared__ __hip_bfloat16 rtw[192];                        // 384 B

  // ---- early global prefetch (no LDS dependency) ----
  B2 b_s1 = { *(const floatx4*)(e1b1 + cb + quad * 4),
              *(const floatx4*)(e1b1 + cb + 16 + quad * 4) };
  WK wk_s1;
#pragma unroll
  for (int ct = 0; ct < 2; ++ct)
    wk_s1.k[ct] = *(const bf16x8*)(wt + O_E1W1P + (cb + ct * 16 + nl) * 32 + quad * 8);

  // ---- stage 0: pre_msg staging ----
  for (int i = tid; i < 96 * PXW; i += 512) {
    int row = i >> 3, c = i & 7;
    int e = row % 6;
    float v = 0.f;
    if (c < 3)      { int rr = row + ((e == 5) ? -5 : 1); v = x[gx + rr * 3 + c]; }
    else if (c < 6) v = x[gx + row * 3 + (c - 3)];
    pxb[i] = __float2bfloat16(v);
  }
  __syncthreads();

  // ---- helpers ----
  auto ldb = [&](const float* p, int ofs) {
    B2 r;
    r.v[0] = *(const floatx4*)(p + ofs + cb + quad * 4);
    r.v[1] = *(const floatx4*)(p + ofs + cb + 16 + quad * 4);
    return r;
  };
  auto initv = [&](floatx4 (&a)[3][2], const B2& b) {
#pragma unroll
    for (int mt = 0; mt < 3; ++mt)
#pragma unroll
      for (int ct = 0; ct < 2; ++ct) a[mt][ct] = b.v[ct];
  };
  auto loadW128 = [&](int wofs) {
    W2 w;
#pragma unroll
    for (int ct = 0; ct < 2; ++ct) {
      const __bf16* p = wt + wofs + (cb + ct * 16 + nl) * 128 + quad * 8;
#pragma unroll
      for (int ks = 0; ks < 4; ++ks) w.b[ct][ks] = *(const bf16x8*)(p + ks * 32);
    }
    return w;
  };
  auto loadW256h = [&](int wofs, int kh) {
    W2 w;
#pragma unroll
    for (int ct = 0; ct < 2; ++ct) {
      const __bf16* p = wt + wofs + (cb + ct * 16 + nl) * 256 + kh * 128 + quad * 8;
#pragma unroll
      for (int ks = 0; ks < 4; ++ks) w.b[ct][ks] = *(const bf16x8*)(p + ks * 32);
    }
    return w;
  };
  auto loadWK = [&](int wofs) {
    WK w;
#pragma unroll
    for (int ct = 0; ct < 2; ++ct)
      w.k[ct] = *(const bf16x8*)(wt + wofs + (cb + ct * 16 + nl) * 32 + quad * 8);
    return w;
  };

  // K=128 GEMM, ct=2 sharing: one B read feeds 2 MFMAs. sched_barrier per ks
  // bounds in-flight B-frags to 3 reads (12 VGPRs) — the R5/R6 spill fix.
  auto gemmP = [&](floatx4 (&acc)[3][2], const W2& w, const __hip_bfloat16* in,
                   bool shift) {
    const __bf16* ab = (const __bf16*)(const void*)in;
    int rows[3];
#pragma unroll
    for (int mt = 0; mt < 3; ++mt) {
      int r = rb + mt * 16 + nl;
      rows[mt] = shift ? (r + ((r % 6 == 5) ? -5 : 1)) : r;
    }
#pragma unroll
    for (int ks = 0; ks < 4; ++ks) {
      int kk = ks * 32 + quad * 8;
#pragma unroll
      for (int mt = 0; mt < 3; ++mt) {
        bf16x8 b = *(const bf16x8*)(ab + SWZ(rows[mt], kk));
#pragma unroll
        for (int ct = 0; ct < 2; ++ct)
          acc[mt][ct] = __builtin_amdgcn_mfma_f32_16x16x32_bf16(w.b[ct][ks], b, acc[mt][ct], 0, 0, 0);
      }
      SCHED;
    }
  };
  // K=32 GEMM vs pxb; only quad 0 carries data.
  auto gemm32 = [&](floatx4 (&acc)[3][2], const WK& w) {
    const __bf16* pb = (const __bf16*)(const void*)pxb;
#pragma unroll
    for (int mt = 0; mt < 3; ++mt) {
      bf16x8 b = {0, 0, 0, 0, 0, 0, 0, 0};
      if (quad == 0) b = *(const bf16x8*)(pb + (rb + mt * 16 + nl) * PXW);
#pragma unroll
      for (int ct = 0; ct < 2; ++ct)
        acc[mt][ct] = __builtin_amdgcn_mfma_f32_16x16x32_bf16(w.k[ct], b, acc[mt][ct], 0, 0, 0);
    }
  };
  // s10: both message types share the single pxb read per mt.
  auto gemm32dual = [&](floatx4 (&a1)[3][2], const WK& w1,
                        floatx4 (&a2)[3][2], const WK& w2v) {
    const __bf16* pb = (const __bf16*)(const void*)pxb;
#pragma unroll
    for (int mt = 0; mt < 3; ++mt) {
      bf16x8 b = {0, 0, 0, 0, 0, 0, 0, 0};
      if (quad == 0) b = *(const bf16x8*)(pb + (rb + mt * 16 + nl) * PXW);
#pragma unroll
      for (int ct = 0; ct < 2; ++ct) {
        a1[mt][ct] = __builtin_amdgcn_mfma_f32_16x16x32_bf16(w1.k[ct], b, a1[mt][ct], 0, 0, 0);
        a2[mt][ct] = __builtin_amdgcn_mfma_f32_16x16x32_bf16(w2v.k[ct], b, a2[mt][ct], 0, 0, 0);
      }
    }
  };
  // epilogue: act 0=none 1=ELU 2=ReLU; shift = write to ring-shifted row (agg)
  auto store_act = [&](floatx4 (&acc)[3][2], int act, __hip_bfloat16* ob,
                       bool shift) {
#pragma unroll
    for (int mt = 0; mt < 3; ++mt) {
      int r = rb + mt * 16 + nl;
      int row = shift ? (r + ((r % 6 == 5) ? -5 : 1)) : r;
      int s = (row & 7) << 3;
#pragma unroll
      for (int ct = 0; ct < 2; ++ct) {
        PK p;
#pragma unroll
        for (int j = 0; j < 4; ++j) {
          float z = acc[mt][ct][j];
          if (act == 1) z = (z > 0.f) ? z : (__expf(z) - 1.f);
          else if (act == 2) z = fmaxf(z, 0.f);
          p.h[j] = __float2bfloat16(z);
        }
        *(bf16x4*)((__bf16*)(void*)ob + row * LDW + ((cb + ct * 16 + quad * 4) ^ s)) = p.v;
      }
    }
  };

  floatx4 acc[3][2], acc2[3][2];

  // s1: hh = ELU(x @ e1w1 + b) [K32] -> bufA; then load e1w2
  initv(acc, b_s1); gemm32(acc, wk_s1);
  SCHED;
  W2 w2 = loadW128(O_E1W2);
  B2 b_s2 = ldb(e1b2, 0);
  store_act(acc, 1, bufA, false);
  __syncthreads();

  // s2: h = ELU(. @ e1w2 + b) -> bufB; then load e2w1 recv-half
  initv(acc, b_s2); gemmP(acc, w2, bufA, false);
  SCHED;
  W2 w3a = loadW256h(O_E2W1, 0);
  B2 b_s3 = ldb(e2b1, 0);
  store_act(acc, 1, bufB, false);
  __syncthreads();

  // s3: ELU([h_recv|h] @ e2w1 + b) -> bufA. w3b loaded up-front (single acc,
  // 64 W-regs + 24 acc + 12 batch = 100 fits); recv gemm hides its latency.
  initv(acc, b_s3);
  W2 w3b = loadW256h(O_E2W1, 1);
  gemmP(acc, w3a, bufB, true);
  gemmP(acc, w3b, bufB, false);
  SCHED;
  W2 w4 = loadW128(O_E2W2);
  B2 b_s4 = ldb(e2b2, 0);
  store_act(acc, 1, bufA, false);
  __syncthreads();

  // s4: he = ELU(. @ e2w2 + b) -> bufC (kept live in LDS through s7)
  initv(acc, b_s4); gemmP(acc, w4, bufA, false);
  SCHED;
  W2 w5 = loadW128(O_E3W1);
  B2 b_s5 = ldb(e3b1, 0);
  store_act(acc, 1, bufC, false);
  __syncthreads();

  // s5: t1 = ELU(he @ e3w1 + b) -> bufA (single acc — no held acc2)
  initv(acc, b_s5); gemmP(acc, w5, bufC, false);
  SCHED;
  W2 w6 = loadW128(O_E3W2);
  B2 b_s6 = ldb(e3b2, 0);
  store_act(acc, 1, bufA, false);
  __syncthreads();

  // s6: h2 = ELU(t1 @ e3w2 + b) -> bufB
  initv(acc, b_s6); gemmP(acc, w6, bufA, false);
  SCHED;
  W2 w7 = loadW256h(O_E4W1, 0);
  B2 b2_s7 = ldb(e4b1, 0);
  store_act(acc, 1, bufB, false);
  __syncthreads();

  // s7: h3h = ELU(e4b1 + h2 @ e4w1[:128] + he @ e4w1[128:]) -> bufA
  // two sequential single-acc gemms from bufB (h2) and bufC (he)
  initv(acc, b2_s7);
  W2 w7b = loadW256h(O_E4W1, 1);
  gemmP(acc, w7, bufB, false);
  gemmP(acc, w7b, bufC, false);
  SCHED;
  W2 w8 = loadW128(O_E4W2);
  B2 b_s8 = ldb(e4b2, 0);
  store_act(acc, 1, bufA, false);
  __syncthreads();

  // s8: h3 = ELU(. @ e4w2 + b) -> bufB; then small s9/s10 weights+biases
  initv(acc, b_s8); gemmP(acc, w8, bufA, false);
  SCHED;
  float ebv = (nl < 2) ? eb_out[nl] : 0.f;
  WK wk10a = loadWK(O_M1T0P);
  WK wk10b = loadWK(O_M1T1P);
  B2 b_m0 = ldb(dmsg_b1, 0);
  B2 b_m1 = ldb(dmsg_b1, 128);
  store_act(acc, 1, bufB, false);
  __syncthreads();

  // s9: logits via N=16-padded MFMA tail (waves 0..5, 16 rows each)
  if (wave < 6) {
    int tile = wave;
    floatx4 lg = {ebv, ebv, ebv, ebv};
    const __bf16* ab = (const __bf16*)(const void*)bufB;
    const __bf16* wp = wt + O_EWOUT + nl * 128 + quad * 8;
#pragma unroll
    for (int ks = 0; ks < 4; ++ks) {
      bf16x8 a = *(const bf16x8*)(ab + SWZ(tile * 16 + nl, ks * 32 + quad * 8));
      bf16x8 b = *(const bf16x8*)(wp + ks * 32);
      lg = __builtin_amdgcn_mfma_f32_16x16x32_bf16(a, b, lg, 0, 0, 0);
    }
    if (nl < 2) {
#pragma unroll
      for (int r = 0; r < 4; ++r)
        rtw[(tile * 16 + quad * 4 + r) * 2 + nl] = __float2bfloat16(lg[r]);
    }
  }
  __syncthreads();

  // s10: softmax; m1 both types [K32] sharing the pxb read: t0->bufA, t1->bufC
  if (tid < 96) {
    float l0 = __bfloat162float(rtw[tid * 2]);
    float l1 = __bfloat162float(rtw[tid * 2 + 1]);
    float mx = fmaxf(l0, l1);
    float ea = __expf(l0 - mx), eb = __expf(l1 - mx);
    float inv = 1.f / (ea + eb);
    rtw[tid * 2] = __float2bfloat16(ea * inv);
    rtw[tid * 2 + 1] = __float2bfloat16(eb * inv);
  }
  initv(acc, b_m0); initv(acc2, b_m1);
  gemm32dual(acc, wk10a, acc2, wk10b);
  store_act(acc, 2, bufA, false);
  store_act(acc2, 2, bufC, false);
  SCHED;
  W2 wm0 = loadW128(O_DM2T0);
  B2 b_d0 = ldb(dmsg_b2, 0);
  B2 b_d1 = ldb(dmsg_b2, 128);
  __syncthreads();

  // s11: msg = rt0*relu(m1t0 @ w2t0 + b) + rt1*relu(m1t1 @ w2t1 + b)
  // weight sets sequenced; dual acc unavoidable here (24+24+32+12 = 92)
  initv(acc, b_d0);  gemmP(acc, wm0, bufA, false);
  SCHED;
  W2 wm1 = loadW128(O_DM2T1);
  initv(acc2, b_d1); gemmP(acc2, wm1, bufC, false);
#pragma unroll
  for (int mt = 0; mt < 3; ++mt) {
    int row = rb + mt * 16 + nl;
    float r0 = __bfloat162float(rtw[row * 2]);
    float r1 = __bfloat162float(rtw[row * 2 + 1]);
#pragma unroll
    for (int ct = 0; ct < 2; ++ct)
#pragma unroll
      for (int j = 0; j < 4; ++j)
        acc[mt][ct][j] = r0 * fmaxf(acc[mt][ct][j], 0.f) + r1 * fmaxf(acc2[mt][ct][j], 0.f);
  }
  SCHED;
  W2 wd1 = loadW128(O_DO1);
  WK wk13 = loadWK(O_DO1XP);
  B2 b_p1 = ldb(dout_b1, 0);
  __syncthreads();

  // s12: agg (edge e -> node (e+1)%6): store msg to ring-shifted rows of bufA
  store_act(acc, 0, bufA, true);
  __syncthreads();

  // s13: p1 = relu([x|agg] @ d_out_w1 + b) -> bufB; then load d_out_w2
  initv(acc, b_p1); gemmP(acc, wd1, bufA, false); gemm32(acc, wk13);
  SCHED;
  W2 wd2 = loadW128(O_DO2);
  B2 b_p2 = ldb(dout_b2, 0);
  store_act(acc, 2, bufB, false);
  __syncthreads();

  // s14: p2 = relu(. @ d_out_w2 + b) -> bufA
  initv(acc, b_p2); gemmP(acc, wd2, bufB, false);
  float b3v = (nl < 3) ? dout_b3[nl] : 0.f;
  store_act(acc, 2, bufA, false);
  __syncthreads();

  // s15: out = x + p2 @ d_out_w3 + b3 (waves 0..5, direct global store)
  if (wave < 6) {
    int tile = wave;
    floatx4 d = {b3v, b3v, b3v, b3v};
    const __bf16* ab = (const __bf16*)(const void*)bufA;
    const __bf16* wp = wt + O_DW3 + nl * 128 + quad * 8;
#pragma unroll
    for (int ks = 0; ks < 4; ++ks) {
      bf16x8 a = *(const bf16x8*)(ab + SWZ(tile * 16 + nl, ks * 32 + quad * 8));
      bf16x8 b = *(const bf16x8*)(wp + ks * 32);
      d = __builtin_amdgcn_mfma_f32_16x16x32_bf16(a, b, d, 0, 0, 0);
    }
    if (nl < 3) {
#pragma unroll
      for (int r = 0; r < 4; ++r) {
        int row = tile * 16 + quad * 4 + r;
        out[gx + row * 3 + nl] = x[gx + row * 3 + nl] + d[r];
      }
    }
  }
}

extern "C" void kernel_launch(void* const* d_in, const int* in_sizes, int n_in,
                              void* d_out, int out_size, void* d_ws, size_t ws_size,
                              hipStream_t stream) {
  const float* x       = (const float*)d_in[0];
  const float* e1w1    = (const float*)d_in[3];
  const float* e1b1    = (const float*)d_in[4];
  const float* e1w2    = (const float*)d_in[5];
  const float* e1b2    = (const float*)d_in[6];
  const float* e2w1    = (const float*)d_in[7];
  const float* e2b1    = (const float*)d_in[8];
  const float* e2w2    = (const float*)d_in[9];
  const float* e2b2    = (const float*)d_in[10];
  const float* e3w1    = (const float*)d_in[11];
  const float* e3b1    = (const float*)d_in[12];
  const float* e3w2    = (const float*)d_in[13];
  const float* e3b2    = (const float*)d_in[14];
  const float* e4w1    = (const float*)d_in[15];
  const float* e4b1    = (const float*)d_in[16];
  const float* e4w2    = (const float*)d_in[17];
  const float* e4b2    = (const float*)d_in[18];
  const float* ew_out  = (const float*)d_in[19];
  const float* eb_out  = (const float*)d_in[20];
  const float* dmsg_w1 = (const float*)d_in[21];
  const float* dmsg_b1 = (const float*)d_in[22];
  const float* dmsg_w2 = (const float*)d_in[23];
  const float* dmsg_b2 = (const float*)d_in[24];
  const float* dout_w1 = (const float*)d_in[25];
  const float* dout_b1 = (const float*)d_in[26];
  const float* dout_w2 = (const float*)d_in[27];
  const float* dout_b2 = (const float*)d_in[28];
  const float* dout_w3 = (const float*)d_in[29];
  const float* dout_b3 = (const float*)d_in[30];

  prep_kernel<<<(WS_ELEMS + 255) / 256, 256, 0, stream>>>(
      e1w2, e2w1, e2w2, e3w1, e3w2, e4w1, e4w2, dmsg_w2, dout_w1, dout_w2,
      ew_out, dout_w3, e1w1, dmsg_w1, (__hip_bfloat16*)d_ws);

  nri_fused<<<32768 / 16, 512, 0, stream>>>(
      x, e1b1, e1b2, e2b1, e2b2, e3b1, e3b2, e4b1, e4b2, eb_out,
      dmsg_b1, dmsg_b2, dout_b1, dout_b2, dout_b3,
      (const __bf16*)d_ws, (float*)d_out);
}

// Round 8
// 327.387 us; speedup vs baseline: 1.2659x; 1.1429x over previous
//
#include <hip/hip_runtime.h>
#include <hip/hip_bf16.h>

typedef __bf16 bf16x8 __attribute__((ext_vector_type(8)));
typedef __bf16 bf16x4 __attribute__((ext_vector_type(4)));
typedef float floatx4 __attribute__((ext_vector_type(4)));
typedef float floatx16 __attribute__((ext_vector_type(16)));

#define LDW 128  // activation row stride (elems); XOR-swizzled, no pad
#define PXW 8    // pre_msg row stride: cols 0..2 recv-x, 3..5 self-x, 6..7 pad

// LDS act tile [96][128] bf16, swizzle: elem = row*128 + (col ^ ((row&7)<<3))
#define SWZ(row, col) ((row) * LDW + ((col) ^ (((row) & 7) << 3)))

#define SCHED __builtin_amdgcn_sched_barrier(0)

// ws layout (bf16 element offsets). Big mats: Wt[n][k]. K32 pads: [128 n][32 k].
// N16 tails: [16 n][128 k].
#define O_E1W2  0
#define O_E2W1  16384
#define O_E2W2  49152
#define O_E3W1  65536
#define O_E3W2  81920
#define O_E4W1  98304
#define O_E4W2  131072
#define O_DM2T0 147456
#define O_DM2T1 163840
#define O_DO1   180224
#define O_DO2   196608
#define O_EWOUT 212992
#define O_DW3   215040
#define O_E1W1P 217088
#define O_M1T0P 221184
#define O_M1T1P 225280
#define O_DO1XP 229376
#define WS_ELEMS 233472

__global__ void prep_kernel(const float* e1w2, const float* e2w1, const float* e2w2,
    const float* e3w1, const float* e3w2, const float* e4w1, const float* e4w2,
    const float* dmsg2, const float* dout1, const float* dout2,
    const float* ew_out, const float* dout_w3, const float* e1w1,
    const float* dmsg_w1, __hip_bfloat16* ws) {
  int idx = blockIdx.x * 256 + threadIdx.x;
  if (idx >= WS_ELEMS) return;
  float v;
  if (idx < O_E2W1)      { int l = idx;           v = e1w2[(l & 127) * 128 + (l >> 7)]; }
  else if (idx < O_E2W2) { int l = idx - O_E2W1;  v = e2w1[(l & 255) * 128 + (l >> 8)]; }
  else if (idx < O_E3W1) { int l = idx - O_E2W2;  v = e2w2[(l & 127) * 128 + (l >> 7)]; }
  else if (idx < O_E3W2) { int l = idx - O_E3W1;  v = e3w1[(l & 127) * 128 + (l >> 7)]; }
  else if (idx < O_E4W1) { int l = idx - O_E3W2;  v = e3w2[(l & 127) * 128 + (l >> 7)]; }
  else if (idx < O_E4W2) { int l = idx - O_E4W1;  v = e4w1[(l & 255) * 128 + (l >> 8)]; }
  else if (idx < O_DM2T0){ int l = idx - O_E4W2;  v = e4w2[(l & 127) * 128 + (l >> 7)]; }
  else if (idx < O_DM2T1){ int l = idx - O_DM2T0; v = dmsg2[(l & 127) * 128 + (l >> 7)]; }
  else if (idx < O_DO1)  { int l = idx - O_DM2T1; v = dmsg2[16384 + (l & 127) * 128 + (l >> 7)]; }
  else if (idx < O_DO2)  { int l = idx - O_DO1;   v = dout1[384 + (l & 127) * 128 + (l >> 7)]; }
  else if (idx < O_EWOUT){ int l = idx - O_DO2;   v = dout2[(l & 127) * 128 + (l >> 7)]; }
  else if (idx < O_DW3)  { int l = idx - O_EWOUT; int n = l >> 7;
                           v = (n < 2) ? ew_out[(l & 127) * 2 + n] : 0.f; }
  else if (idx < O_E1W1P){ int l = idx - O_DW3;   int n = l >> 7;
                           v = (n < 3) ? dout_w3[(l & 127) * 3 + n] : 0.f; }
  else if (idx < O_M1T0P){ int l = idx - O_E1W1P; int n = l >> 5, c = l & 31;
                           v = (c >= 3 && c < 6) ? e1w1[(c - 3) * 128 + n] : 0.f; }
  else if (idx < O_M1T1P){ int l = idx - O_M1T0P; int n = l >> 5, c = l & 31;
                           v = (c < 6) ? dmsg_w1[c * 128 + n] : 0.f; }
  else if (idx < O_DO1XP){ int l = idx - O_M1T1P; int n = l >> 5, c = l & 31;
                           v = (c < 6) ? dmsg_w1[768 + c * 128 + n] : 0.f; }
  else                   { int l = idx - O_DO1XP; int n = l >> 5, c = l & 31;
                           v = (c >= 3 && c < 6) ? dout1[(c - 3) * 128 + n] : 0.f; }
  ws[idx] = __float2bfloat16(v);
}

struct W32 { bf16x8 b[8]; };   // full K=128 weight slice for 32 cols (32 VGPRs)
struct B16 { floatx4 v[4]; };  // bias frag: reg r -> col cb + (r&3)+8*(r>>2)+4*hi
union PK { bf16x4 v; __hip_bfloat16 h[4]; };

// Round-8: 32x32x16 MFMA. One B-read (b128) feeds a 32-col MFMA -> 2x FLOP
// per LDS read vs 16x16x32 (the read-halving ct=2 failed to get 3x on regs).
// 4 waves/block (wave = 32-col slice x 3 row-tiles, per-rt 16-reg acc).
// launch_bounds(256,3): the 2nd arg has empirically set occupancy every round
// (R1:8->4blk, R2:6->3blk, R4:4->2blk) -> 3 waves/SIMD = 3 blocks/CU AND a
// 168-VGPR cap (vs 128) so the W32(32)+acc(16) structure fits with headroom.
// A/B frag layout (32x32x16): elem m|n = lane&31, k = (lane>>5)*8 + e;
// C/D: col(n)=lane&31, row(m)=(reg&3)+8*(reg>>2)+4*(lane>>5)  [guide m74/m101]
__global__ __launch_bounds__(256, 3) void nri_fused(
    const float* __restrict__ x,
    const float* __restrict__ e1b1, const float* __restrict__ e1b2,
    const float* __restrict__ e2b1, const float* __restrict__ e2b2,
    const float* __restrict__ e3b1, const float* __restrict__ e3b2,
    const float* __restrict__ e4b1, const float* __restrict__ e4b2,
    const float* __restrict__ eb_out,
    const float* __restrict__ dmsg_b1, const float* __restrict__ dmsg_b2,
    const float* __restrict__ dout_b1, const float* __restrict__ dout_b2,
    const float* __restrict__ dout_b3,
    const __bf16* __restrict__ wt, float* __restrict__ out)
{
  const int tid  = threadIdx.x;
  const int wave = tid >> 6;
  const int lane = tid & 63;
  const int n32  = lane & 31;   // act-row within tile (B/D col) / weight col (A)
  const int hi   = lane >> 5;   // k-group selector
  const int cb   = wave * 32;   // wave's 32-col slice
  const int gx   = blockIdx.x * 288;

  __shared__ __align__(16) __hip_bfloat16 bufA[96 * LDW];   // 24576 B
  __shared__ __align__(16) __hip_bfloat16 bufB[96 * LDW];   // 24576 B
  __shared__ __align__(16) __hip_bfloat16 pxb[96 * PXW];    // 1536 B
  __shared__ __hip_bfloat16 rtw[192];                        // 384 B

  // ---- early global prefetch ----
  B16 b_s1 = { *(const floatx4*)(e1b1 + cb + 4 * hi),
               *(const floatx4*)(e1b1 + cb + 8 + 4 * hi),
               *(const floatx4*)(e1b1 + cb + 16 + 4 * hi),
               *(const floatx4*)(e1b1 + cb + 24 + 4 * hi) };
  bf16x8 wk1 = *(const bf16x8*)(wt + O_E1W1P + (cb + n32) * 32 + hi * 8);

  // ---- stage 0: pre_msg staging ----
  for (int i = tid; i < 96 * PXW; i += 256) {
    int row = i >> 3, c = i & 7;
    int e = row % 6;
    float v = 0.f;
    if (c < 3)      { int rr = row + ((e == 5) ? -5 : 1); v = x[gx + rr * 3 + c]; }
    else if (c < 6) v = x[gx + row * 3 + (c - 3)];
    pxb[i] = __float2bfloat16(v);
  }
  __syncthreads();

  // ---- helpers ----
  auto ldb = [&](const float* p, int ofs) {
    B16 r;
#pragma unroll
    for (int q = 0; q < 4; ++q)
      r.v[q] = *(const floatx4*)(p + ofs + cb + q * 8 + 4 * hi);
    return r;
  };
  auto initacc = [&](const B16& b) {
    floatx16 a;
#pragma unroll
    for (int r = 0; r < 16; ++r) a[r] = b.v[r >> 2][r & 3];
    return a;
  };
  auto loadW = [&](int wofs) {
    W32 w;
    const __bf16* p = wt + wofs + (cb + n32) * 128 + hi * 8;
#pragma unroll
    for (int ks = 0; ks < 8; ++ks) w.b[ks] = *(const bf16x8*)(p + ks * 16);
    return w;
  };
  auto loadW256h = [&](int wofs, int kh) {
    W32 w;
    const __bf16* p = wt + wofs + (cb + n32) * 256 + kh * 128 + hi * 8;
#pragma unroll
    for (int ks = 0; ks < 8; ++ks) w.b[ks] = *(const bf16x8*)(p + ks * 16);
    return w;
  };
  auto rowOf = [&](int rt, bool shift) {
    int r = rt * 32 + n32;
    return shift ? (r + ((r % 6 == 5) ? -5 : 1)) : r;
  };
  // K=128 GEMM into one 32x32 tile: 8 reads, 8 MFMAs. Mid-gemm SCHED bounds
  // the in-flight read batch to 4 (16 VGPRs).
  auto gemm128 = [&](floatx16& a, const W32& w, const __hip_bfloat16* buf, int row) {
    const __bf16* ab = (const __bf16*)(const void*)buf;
#pragma unroll
    for (int ks = 0; ks < 8; ++ks) {
      bf16x8 bb = *(const bf16x8*)(ab + SWZ(row, ks * 16 + hi * 8));
      a = __builtin_amdgcn_mfma_f32_32x32x16_bf16(w.b[ks], bb, a, 0, 0, 0);
      if (ks == 3) SCHED;
    }
  };
  // K=16 GEMM vs pxb (real k<8; hi=1 lanes supply zeros, weight k8..15 = 0)
  auto gemmK = [&](floatx16& a, bf16x8 wk, int row) {
    bf16x8 bb = {0, 0, 0, 0, 0, 0, 0, 0};
    if (hi == 0)
      bb = *(const bf16x8*)((const __bf16*)(const void*)pxb + row * PXW);
    a = __builtin_amdgcn_mfma_f32_32x32x16_bf16(wk, bb, a, 0, 0, 0);
  };
  // epilogue: regs 4q..4q+3 -> cols cb + 8q + 4hi .. +3 of row `orow`
  auto store16 = [&](const floatx16& a, int act, __hip_bfloat16* ob, int orow) {
    int s = (orow & 7) << 3;
#pragma unroll
    for (int q = 0; q < 4; ++q) {
      PK p;
#pragma unroll
      for (int j = 0; j < 4; ++j) {
        float z = a[q * 4 + j];
        if (act == 1) z = (z > 0.f) ? z : (__expf(z) - 1.f);
        else if (act == 2) z = fmaxf(z, 0.f);
        p.h[j] = __float2bfloat16(z);
      }
      *(bf16x4*)((__bf16*)(void*)ob + orow * LDW + ((cb + q * 8 + 4 * hi) ^ s)) = p.v;
    }
  };

  floatx16 acc;

  // s1: hh = ELU(x @ e1w1 + b) [K32 pad] -> bufA
#pragma unroll
  for (int rt = 0; rt < 3; ++rt) {
    acc = initacc(b_s1);
    gemmK(acc, wk1, rt * 32 + n32);
    store16(acc, 1, bufA, rt * 32 + n32);
  }
  SCHED;
  W32 w2 = loadW(O_E1W2);
  B16 b_s2 = ldb(e1b2, 0);
  __syncthreads();

  // s2: h = ELU(. @ e1w2 + b) -> bufB
#pragma unroll
  for (int rt = 0; rt < 3; ++rt) {
    acc = initacc(b_s2);
    gemm128(acc, w2, bufA, rt * 32 + n32);
    store16(acc, 1, bufB, rt * 32 + n32);
  }
  SCHED;
  W32 w3a = loadW256h(O_E2W1, 0);
  W32 w3b = loadW256h(O_E2W1, 1);
  B16 b_s3 = ldb(e2b1, 0);
  __syncthreads();

  // s3: ELU([h_recv|h] @ e2w1 + b) -> bufA  (K=256: shifted rows then own)
#pragma unroll
  for (int rt = 0; rt < 3; ++rt) {
    acc = initacc(b_s3);
    gemm128(acc, w3a, bufB, rowOf(rt, true));
    gemm128(acc, w3b, bufB, rt * 32 + n32);
    store16(acc, 1, bufA, rt * 32 + n32);
  }
  SCHED;
  W32 w4 = loadW(O_E2W2);
  B16 b_s4 = ldb(e2b2, 0);
  __syncthreads();

  // s4: he = ELU(. @ e2w2 + b) -> bufB
#pragma unroll
  for (int rt = 0; rt < 3; ++rt) {
    acc = initacc(b_s4);
    gemm128(acc, w4, bufA, rt * 32 + n32);
    store16(acc, 1, bufB, rt * 32 + n32);
  }
  SCHED;
  W32 w5 = loadW(O_E3W1);
  B16 b_s5 = ldb(e3b1, 0);
  __syncthreads();

  // s5a: t1 = ELU(he @ e3w1 + b) -> bufA
#pragma unroll
  for (int rt = 0; rt < 3; ++rt) {
    acc = initacc(b_s5);
    gemm128(acc, w5, bufB, rt * 32 + n32);
    store16(acc, 1, bufA, rt * 32 + n32);
  }
  SCHED;
  // s5b: acc2[rt] = e4b1 + he @ e4w1[k 128:]  (held, 48 VGPRs)
  W32 w5b = loadW256h(O_E4W1, 1);
  B16 b2_s5 = ldb(e4b1, 0);
  floatx16 acc2[3];
#pragma unroll
  for (int rt = 0; rt < 3; ++rt) {
    acc2[rt] = initacc(b2_s5);
    gemm128(acc2[rt], w5b, bufB, rt * 32 + n32);
  }
  SCHED;
  W32 w6 = loadW(O_E3W2);
  B16 b_s6 = ldb(e3b2, 0);
  __syncthreads();

  // s6: h2 = ELU(t1 @ e3w2 + b) -> bufB (he dead)
#pragma unroll
  for (int rt = 0; rt < 3; ++rt) {
    acc = initacc(b_s6);
    gemm128(acc, w6, bufA, rt * 32 + n32);
    store16(acc, 1, bufB, rt * 32 + n32);
  }
  SCHED;
  W32 w7 = loadW256h(O_E4W1, 0);
  __syncthreads();

  // s7: h3h = ELU(acc2 + h2 @ e4w1[k :128]) -> bufA
#pragma unroll
  for (int rt = 0; rt < 3; ++rt) {
    gemm128(acc2[rt], w7, bufB, rt * 32 + n32);
    store16(acc2[rt], 1, bufA, rt * 32 + n32);
  }
  SCHED;
  W32 w8 = loadW(O_E4W2);
  B16 b_s8 = ldb(e4b2, 0);
  __syncthreads();

  // s8: h3 = ELU(. @ e4w2 + b) -> bufB
#pragma unroll
  for (int rt = 0; rt < 3; ++rt) {
    acc = initacc(b_s8);
    gemm128(acc, w8, bufA, rt * 32 + n32);
    store16(acc, 1, bufB, rt * 32 + n32);
  }
  SCHED;
  float ebv = (n32 < 2) ? eb_out[n32] : 0.f;
  bf16x8 wk10a = *(const bf16x8*)(wt + O_M1T0P + (cb + n32) * 32 + hi * 8);
  bf16x8 wk10b = *(const bf16x8*)(wt + O_M1T1P + (cb + n32) * 32 + hi * 8);
  B16 b_m0 = ldb(dmsg_b1, 0);
  B16 b_m1 = ldb(dmsg_b1, 128);
  __syncthreads();

  // s9: logits (old orientation: A = acts rows, B = ew_out cols; waves 0..2)
  if (wave < 3) {
    floatx16 lg;
#pragma unroll
    for (int r = 0; r < 16; ++r) lg[r] = ebv;
    const __bf16* ab = (const __bf16*)(const void*)bufB;
#pragma unroll
    for (int ks = 0; ks < 8; ++ks) {
      bf16x8 a = *(const bf16x8*)(ab + SWZ(wave * 32 + n32, ks * 16 + hi * 8));
      bf16x8 b = *(const bf16x8*)(wt + O_EWOUT + n32 * 128 + ks * 16 + hi * 8);
      lg = __builtin_amdgcn_mfma_f32_32x32x16_bf16(a, b, lg, 0, 0, 0);
    }
    if (n32 < 2) {
#pragma unroll
      for (int r = 0; r < 16; ++r) {
        int row = wave * 32 + (r & 3) + 8 * (r >> 2) + 4 * hi;
        rtw[row * 2 + n32] = __float2bfloat16(lg[r]);
      }
    }
  }
  __syncthreads();

  // s10: softmax; m1 t0 -> bufA, t1 -> bufB [K32 pads]
  if (tid < 96) {
    float l0 = __bfloat162float(rtw[tid * 2]);
    float l1 = __bfloat162float(rtw[tid * 2 + 1]);
    float mx = fmaxf(l0, l1);
    float ea = __expf(l0 - mx), eb = __expf(l1 - mx);
    float inv = 1.f / (ea + eb);
    rtw[tid * 2] = __float2bfloat16(ea * inv);
    rtw[tid * 2 + 1] = __float2bfloat16(eb * inv);
  }
#pragma unroll
  for (int rt = 0; rt < 3; ++rt) {
    acc = initacc(b_m0);
    gemmK(acc, wk10a, rt * 32 + n32);
    store16(acc, 2, bufA, rt * 32 + n32);
  }
#pragma unroll
  for (int rt = 0; rt < 3; ++rt) {
    acc = initacc(b_m1);
    gemmK(acc, wk10b, rt * 32 + n32);
    store16(acc, 2, bufB, rt * 32 + n32);
  }
  SCHED;
  W32 wm0 = loadW(O_DM2T0);
  B16 b_d0 = ldb(dmsg_b2, 0);
  B16 b_d1 = ldb(dmsg_b2, 128);
  __syncthreads();

  // s11: msg = rt0*relu(m1t0 @ w2t0 + b) + rt1*relu(m1t1 @ w2t1 + b)
  // phase 1: all rt with wm0 (held msg[3] = 48 regs); then wm0 dies, wm1 loads
  floatx16 msg[3];
#pragma unroll
  for (int rt = 0; rt < 3; ++rt) {
    msg[rt] = initacc(b_d0);
    gemm128(msg[rt], wm0, bufA, rt * 32 + n32);
  }
  SCHED;
  W32 wm1 = loadW(O_DM2T1);
#pragma unroll
  for (int rt = 0; rt < 3; ++rt) {
    acc = initacc(b_d1);
    gemm128(acc, wm1, bufB, rt * 32 + n32);
    float r0 = __bfloat162float(rtw[(rt * 32 + n32) * 2]);
    float r1 = __bfloat162float(rtw[(rt * 32 + n32) * 2 + 1]);
#pragma unroll
    for (int j = 0; j < 16; ++j)
      msg[rt][j] = r0 * fmaxf(msg[rt][j], 0.f) + r1 * fmaxf(acc[j], 0.f);
  }
  SCHED;
  W32 wd1 = loadW(O_DO1);
  bf16x8 wk13 = *(const bf16x8*)(wt + O_DO1XP + (cb + n32) * 32 + hi * 8);
  B16 b_p1 = ldb(dout_b1, 0);
  __syncthreads();   // all reads of bufA/bufB complete

  // s12: agg (edge e -> node (e+1)%6): shifted store -> bufA
#pragma unroll
  for (int rt = 0; rt < 3; ++rt)
    store16(msg[rt], 0, bufA, rowOf(rt, true));
  __syncthreads();

  // s13: p1 = relu([x|agg] @ d_out_w1 + b) -> bufB
#pragma unroll
  for (int rt = 0; rt < 3; ++rt) {
    acc = initacc(b_p1);
    gemm128(acc, wd1, bufA, rt * 32 + n32);
    gemmK(acc, wk13, rt * 32 + n32);
    store16(acc, 2, bufB, rt * 32 + n32);
  }
  SCHED;
  W32 wd2 = loadW(O_DO2);
  B16 b_p2 = ldb(dout_b2, 0);
  __syncthreads();

  // s14: p2 = relu(. @ d_out_w2 + b) -> bufA
#pragma unroll
  for (int rt = 0; rt < 3; ++rt) {
    acc = initacc(b_p2);
    gemm128(acc, wd2, bufB, rt * 32 + n32);
    store16(acc, 2, bufA, rt * 32 + n32);
  }
  float b3v = (n32 < 3) ? dout_b3[n32] : 0.f;
  __syncthreads();

  // s15: out = x + p2 @ d_out_w3 + b3 (old orientation; waves 0..2)
  if (wave < 3) {
    floatx16 d;
#pragma unroll
    for (int r = 0; r < 16; ++r) d[r] = b3v;
    const __bf16* ab = (const __bf16*)(const void*)bufA;
#pragma unroll
    for (int ks = 0; ks < 8; ++ks) {
      bf16x8 a = *(const bf16x8*)(ab + SWZ(wave * 32 + n32, ks * 16 + hi * 8));
      bf16x8 b = *(const bf16x8*)(wt + O_DW3 + n32 * 128 + ks * 16 + hi * 8);
      d = __builtin_amdgcn_mfma_f32_32x32x16_bf16(a, b, d, 0, 0, 0);
    }
    if (n32 < 3) {
#pragma unroll
      for (int r = 0; r < 16; ++r) {
        int row = wave * 32 + (r & 3) + 8 * (r >> 2) + 4 * hi;
        out[gx + row * 3 + n32] = x[gx + row * 3 + n32] + d[r];
      }
    }
  }
}

extern "C" void kernel_launch(void* const* d_in, const int* in_sizes, int n_in,
                              void* d_out, int out_size, void* d_ws, size_t ws_size,
                              hipStream_t stream) {
  const float* x       = (const float*)d_in[0];
  const float* e1w1    = (const float*)d_in[3];
  const float* e1b1    = (const float*)d_in[4];
  const float* e1w2    = (const float*)d_in[5];
  const float* e1b2    = (const float*)d_in[6];
  const float* e2w1    = (const float*)d_in[7];
  const float* e2b1    = (const float*)d_in[8];
  const float* e2w2    = (const float*)d_in[9];
  const float* e2b2    = (const float*)d_in[10];
  const float* e3w1    = (const float*)d_in[11];
  const float* e3b1    = (const float*)d_in[12];
  const float* e3w2    = (const float*)d_in[13];
  const float* e3b2    = (const float*)d_in[14];
  const float* e4w1    = (const float*)d_in[15];
  const float* e4b1    = (const float*)d_in[16];
  const float* e4w2    = (const float*)d_in[17];
  const float* e4b2    = (const float*)d_in[18];
  const float* ew_out  = (const float*)d_in[19];
  const float* eb_out  = (const float*)d_in[20];
  const float* dmsg_w1 = (const float*)d_in[21];
  const float* dmsg_b1 = (const float*)d_in[22];
  const float* dmsg_w2 = (const float*)d_in[23];
  const float* dmsg_b2 = (const float*)d_in[24];
  const float* dout_w1 = (const float*)d_in[25];
  const float* dout_b1 = (const float*)d_in[26];
  const float* dout_w2 = (const float*)d_in[27];
  const float* dout_b2 = (const float*)d_in[28];
  const float* dout_w3 = (const float*)d_in[29];
  const float* dout_b3 = (const float*)d_in[30];

  prep_kernel<<<(WS_ELEMS + 255) / 256, 256, 0, stream>>>(
      e1w2, e2w1, e2w2, e3w1, e3w2, e4w1, e4w2, dmsg_w2, dout_w1, dout_w2,
      ew_out, dout_w3, e1w1, dmsg_w1, (__hip_bfloat16*)d_ws);

  // 16 graphs (96 rows) per block, 4 waves of 32-col slices
  nri_fused<<<32768 / 16, 256, 0, stream>>>(
      x, e1b1, e1b2, e2b1, e2b2, e3b1, e3b2, e4b1, e4b2, eb_out,
      dmsg_b1, dmsg_b2, dout_b1, dout_b2, dout_b3,
      (const __bf16*)d_ws, (float*)d_out);
}